// Round 12
// baseline (190.969 us; speedup 1.0000x reference)
//
#include <hip/hip_runtime.h>
#include <hip/hip_bf16.h>

// MaskedAttentionLayer: B=4, N=4096, D=256, fp32 in/out.
// mask keeps strictly-future (m>n); softmax over QUERY axis (per-column).
// O = E @ (V/colsum), E = exp(S/16); col m=0 fully masked -> V[b,0,:]/4096.
//
// Structure: materialize E (unnormalized exp, bf16, upper-tri tiles only,
// FRAGMENT-MAJOR layout) -> k_scores (S^T MFMA + fused colsum, 1 barrier/
// step, contiguous E stores); k_pv = streaming GEMM, E direct-to-register
// (coalesced frag loads, no LDS), V dbuf LDS via gl16, 1 barrier/step.

typedef float f32x4 __attribute__((ext_vector_type(4)));
typedef __bf16 bf16x8 __attribute__((ext_vector_type(8)));
typedef __bf16 bf16x4 __attribute__((ext_vector_type(4)));

#define MFMA16(a, b, c) __builtin_amdgcn_mfma_f32_16x16x32_bf16((a), (b), (c), 0, 0, 0)

constexpr int SEQ = 4096;
constexpr int DIM = 256;

__host__ __device__ inline int tri(int x) { return (x * (x + 1)) >> 1; }

// async global->LDS DMA, 16B/lane (dest = wave-uniform base + lane*16)
__device__ __forceinline__ void gl16(const __bf16* g, __bf16* l) {
  __builtin_amdgcn_global_load_lds((const __attribute__((address_space(1))) void*)g,
                                   (__attribute__((address_space(3))) void*)l, 16, 0, 0);
}

// ---------------------------------------------------------------- k_prep
__global__ void k_prep(const float* __restrict__ Wq, const float* __restrict__ Wk,
                       const float* __restrict__ Wv, __bf16* __restrict__ Wb,
                       float* __restrict__ colsum) {
  int i = blockIdx.x * 256 + threadIdx.x;
  if (i < 3 * 65536) {
    const float* src = (i < 65536) ? Wq : (i < 131072 ? Wk : Wv);
    Wb[i] = (__bf16)src[i & 65535];
  }
  if (i < 4 * SEQ) colsum[i] = 0.f;
}

// ---------------------------------------------------------------- k_qkv
// (r6-verified, unchanged)
__global__ __launch_bounds__(256, 2) void k_qkv(const float* __restrict__ x,
                                                const __bf16* __restrict__ Wb,
                                                __bf16* __restrict__ Qb,
                                                __bf16* __restrict__ Kb,
                                                __bf16* __restrict__ Vb) {
  __shared__ __bf16 wsh[64][264];
  const int t = threadIdx.x, lane = t & 63, w = t >> 6;
  const int ln = lane & 15, quad = lane >> 4, q8 = quad * 8;
  const int i0 = blockIdx.x * 64;
  bf16x8 xa[8];
#pragma unroll
  for (int kf = 0; kf < 8; ++kf) {
    const float* src = &x[(size_t)(i0 + w * 16 + ln) * DIM + kf * 32 + q8];
    float4 v0 = *(const float4*)&src[0];
    float4 v1 = *(const float4*)&src[4];
    xa[kf] = bf16x8{(__bf16)v0.x, (__bf16)v0.y, (__bf16)v0.z, (__bf16)v0.w,
                    (__bf16)v1.x, (__bf16)v1.y, (__bf16)v1.z, (__bf16)v1.w};
  }
  for (int zj = 0; zj < 12; ++zj) {
    const int z = zj >> 2, j0 = (zj & 3) * 64;
    const __bf16* W = Wb + z * 65536 + j0 * 256;
    bf16x8 stg[8];
#pragma unroll
    for (int i = 0; i < 8; ++i) stg[i] = *(const bf16x8*)&W[(t + i * 256) * 8];
    __syncthreads();
#pragma unroll
    for (int i = 0; i < 8; ++i)
      *(bf16x8*)&wsh[(t >> 5) + i * 8][(t & 31) * 8] = stg[i];
    __syncthreads();
    f32x4 acc[4] = {};
#pragma unroll
    for (int kf = 0; kf < 8; ++kf) {
      bf16x8 bb[4];
#pragma unroll
      for (int tj = 0; tj < 4; ++tj)
        bb[tj] = *(bf16x8*)&wsh[tj * 16 + ln][kf * 32 + q8];
#pragma unroll
      for (int tj = 0; tj < 4; ++tj) acc[tj] = MFMA16(xa[kf], bb[tj], acc[tj]);
    }
    __bf16* Out = (z == 0) ? Qb : (z == 1 ? Kb : Vb);
#pragma unroll
    for (int tj = 0; tj < 4; ++tj)
#pragma unroll
      for (int r = 0; r < 4; ++r) {
        int row = i0 + w * 16 + quad * 4 + r;
        int col = j0 + tj * 16 + ln;
        Out[(size_t)row * DIM + col] = (__bf16)acc[tj][r];
      }
  }
}

// ---------------------------------------------------------------- k_scores
// E-tile(nc, mt) = masked exp(q.k/16), stored FRAGMENT-MAJOR for k_pv's
// A-operand: elem addr = (frag*64 + lane_c)*8 + j, frag = kf*4 + tn
// (tn: n_local/16), lane_c = (n&15) + 16*((m%32)/8), j = m%8.
// Producer (C-layout: n=tn*16+ln, m=w*16+quad*4+r): frag=(w>>1)*4+tn,
// lane_c = ln + 16*((w&1)*2 + (quad>>1)), j0=(quad&1)*4 -> bf16x4 store;
// each wave fills a contiguous 512B block per tn. colsum fused (atomics).
__global__ __launch_bounds__(256, 2) void k_scores(const __bf16* __restrict__ Qb,
                                                   const __bf16* __restrict__ Kb,
                                                   __bf16* __restrict__ E,
                                                   float* __restrict__ colsum,
                                                   int mtLo, int triLo, int ntiles) {
  __shared__ __bf16 qsh[2 * 64 * 256];  // 64 KB dbuf
  const int t = threadIdx.x, lane = t & 63, w = t >> 6;
  const int ln = lane & 15, quad = lane >> 4, q8 = quad * 8;
  const int bid = blockIdx.x;
  const int b = (bid & 7) >> 1;                    // XCD-pair pinned batch
  const int rest = ((bid >> 3) << 1) | (bid & 1);  // 0..4*nmt-1
  const int mt = mtLo + (rest >> 2);
  const int s = rest & 3;
  if (s > mt) return;
  const int m0 = mt * 64;
  const __bf16* Qp = Qb + (size_t)b * SEQ * DIM;
  const __bf16* Kp = Kb + (size_t)b * SEQ * DIM;
  bf16x8 kb[8];
#pragma unroll
  for (int kf = 0; kf < 8; ++kf)
    kb[kf] = *(const bf16x8*)&Kp[(size_t)(m0 + w * 16 + ln) * DIM + kf * 32 + q8];
  auto stageq = [&](int ncv, int buf) {
    const __bf16* src = Qp + (size_t)ncv * 16384;
#pragma unroll
    for (int i2 = 0; i2 < 8; ++i2) {
      int sl = t + i2 * 256;
      int row = sl >> 5, g = sl & 31;
      gl16(&src[row * 256 + ((g ^ (row & 15)) << 3)], &qsh[buf * 16384 + sl * 8]);
    }
  };
  float csum4[4] = {0.f, 0.f, 0.f, 0.f};
  // fragment-major store indices (constant per lane)
  const int fragBase = (w >> 1) * 4;                       // + tn
  const int lane_c = ln + 16 * ((w & 1) * 2 + (quad >> 1));
  const int j0 = (quad & 1) * 4;
  int nc = s, cur = 0;
  if (nc <= mt) stageq(nc, 0);
  for (; nc <= mt; nc += 4, cur ^= 1) {
    __syncthreads();  // Q[cur] staged (full-step overlap)
    if (nc + 4 <= mt) stageq(nc + 4, cur ^ 1);
    f32x4 accST[4] = {};
#pragma unroll
    for (int kf = 0; kf < 8; ++kf) {
#pragma unroll
      for (int tn = 0; tn < 4; ++tn) {
        int row = tn * 16 + ln;
        bf16x8 bq = *(const bf16x8*)&qsh[cur * 16384 + row * 256 +
                                         (((kf * 4 + quad) ^ ln) << 3)];
        accST[tn] = MFMA16(kb[kf], bq, accST[tn]);
      }
    }
    __bf16* Et = E + ((size_t)b * ntiles + (tri(mt) - triLo) + nc) * 4096;
#pragma unroll
    for (int tn = 0; tn < 4; ++tn) {
      int n_g = nc * 64 + tn * 16 + ln;
      int mb = m0 + w * 16 + quad * 4;
      bf16x4 pk;
#pragma unroll
      for (int r = 0; r < 4; ++r) {
        float e = (n_g < mb + r) ? __expf(accST[tn][r] * 0.0625f) : 0.f;
        csum4[r] += e;
        pk[r] = (__bf16)e;
      }
      *(bf16x4*)&Et[((fragBase + tn) * 64 + lane_c) * 8 + j0] = pk;
    }
  }
#pragma unroll
  for (int r = 0; r < 4; ++r) {
    float v = csum4[r];
    v += __shfl_xor(v, 1);
    v += __shfl_xor(v, 2);
    v += __shfl_xor(v, 4);
    v += __shfl_xor(v, 8);
    if (ln == 0) atomicAdd(&colsum[b * SEQ + m0 + w * 16 + quad * 4 + r], v);
  }
}

// ---------------------------------------------------------------- k_vpt
// (r10-verified, unchanged) swizzled VpTblk[b][mblk][d][m'] = V/colsum.
__global__ void k_vpt(const __bf16* __restrict__ Vb, const float* __restrict__ colsum,
                      __bf16* __restrict__ VpT, int mtLo) {
  __shared__ __bf16 tile[64][72];
  const int t = threadIdx.x;
  const int b = blockIdx.z;
  const int mblk = mtLo + blockIdx.x;
  const int m0 = mblk * 64, d0 = blockIdx.y * 64;
  {
    int row = t >> 2, part = t & 3;
    float cs = colsum[b * SEQ + m0 + row];
    float inv = (m0 + row == 0) ? (1.0f / 4096.0f) : (1.0f / cs);
#pragma unroll
    for (int i = 0; i < 2; ++i) {
      int c = part * 2 + i;
      bf16x8 v = *(const bf16x8*)&Vb[(size_t)(b * SEQ + m0 + row) * DIM + d0 + c * 8];
      bf16x8 o;
#pragma unroll
      for (int j = 0; j < 8; ++j) o[j] = (__bf16)((float)v[j] * inv);
      *(bf16x8*)&tile[row][c * 8] = o;
    }
  }
  __syncthreads();
  {
    int row = t >> 2, part = t & 3;  // row = d-local
#pragma unroll
    for (int i = 0; i < 2; ++i) {
      int c = part * 2 + i;  // logical m-part
      bf16x8 o;
#pragma unroll
      for (int j = 0; j < 8; ++j) o[j] = tile[c * 8 + j][row];
      *(bf16x8*)&VpT[(size_t)((b * 64 + mblk) * 256 + d0 + row) * 64 +
                     ((c ^ (row & 7)) << 3)] = o;
    }
  }
}

// ---------------------------------------------------------------- k_pv v3
// O[32n-tile][128d-half] (+)= sum_mt E-half . VpT-half. E read DIRECT TO
// REGISTERS (4 coalesced dwordx4 frag loads/wave/step, 1-step rotation
// eC<-eN); V dbuf LDS via gl16 (32 KB total), 1 barrier/step. Mapping as
// r11: idx pair = same nt32 + dh 0/1; p interleaves long/short nt.
__global__ __launch_bounds__(256, 4) void k_pv(const __bf16* __restrict__ E,
                                               const __bf16* __restrict__ VpT,
                                               const __bf16* __restrict__ Vb,
                                               float* __restrict__ out,
                                               int mtLo, int mtHi, int triLo,
                                               int ntiles) {
  __shared__ __bf16 vsh[2 * 128 * 64];  // 32768 B dbuf
  const int t = threadIdx.x, lane = t & 63, w = t >> 6;
  const int ln = lane & 15, quad = lane >> 4;
  const int bid = blockIdx.x;
  const int b = (bid & 7) >> 1;                   // XCD-pair pinned batch
  const int idx = ((bid >> 3) << 1) | (bid & 1);  // 0..4*mtHi-1
  const int p = idx >> 1, dh = idx & 1;
  const int nt32 = (p & 1) ? (2 * mtHi - 1 - (p >> 1)) : (p >> 1);
  const int nc = nt32 >> 1, half = nt32 & 1;      // 64-row E tile + half
  const int mtStart = (nc > mtLo) ? nc : mtLo;
  const int n0 = nt32 * 32;
  const __bf16* Vt = VpT + (size_t)b * SEQ * DIM;
  const __bf16* Ebase = E + ((size_t)b * ntiles - triLo + nc) * 4096;
  auto loadE = [&](int msv, bf16x8 e[2][2]) {
    const __bf16* ep = Ebase + (size_t)tri(msv) * 4096;
#pragma unroll
    for (int kf = 0; kf < 2; ++kf)
#pragma unroll
      for (int tn = 0; tn < 2; ++tn)
        e[tn][kf] = *(const bf16x8*)&ep[((kf * 4 + half * 2 + tn) * 64 + lane) * 8];
  };
  auto stageVp = [&](int msv, int buf) {
    const __bf16* vp = Vt + (size_t)msv * 16384 + dh * 8192;
#pragma unroll
    for (int i2 = 0; i2 < 4; ++i2) {
      int sl = t + i2 * 256;
      gl16(&vp[sl * 8], &vsh[buf * 8192 + sl * 8]);
    }
  };
  f32x4 accO[2][2] = {};  // [tn][td]
  bf16x8 eN[2][2], eC[2][2];
  int cur = 0;
  if (mtHi - 1 >= mtStart) { loadE(mtHi - 1, eN); stageVp(mtHi - 1, 0); }
  for (int ms = mtHi - 1; ms >= mtStart; --ms, cur ^= 1) {
    __syncthreads();  // vsh[cur] + eN arrived (vmcnt drain at barrier)
#pragma unroll
    for (int tn = 0; tn < 2; ++tn)
#pragma unroll
      for (int kf = 0; kf < 2; ++kf) eC[tn][kf] = eN[tn][kf];
    if (ms - 1 >= mtStart) { loadE(ms - 1, eN); stageVp(ms - 1, cur ^ 1); }
#pragma unroll
    for (int kf = 0; kf < 2; ++kf) {
      bf16x8 bb[2];
#pragma unroll
      for (int td = 0; td < 2; ++td) {
        int rl = w * 32 + td * 16 + ln;  // d within the 128-d half
        bb[td] = *(const bf16x8*)&vsh[cur * 8192 + rl * 64 +
                                      (((kf * 4 + quad) ^ (rl & 7)) << 3)];
      }
#pragma unroll
      for (int tn = 0; tn < 2; ++tn)
#pragma unroll
        for (int td = 0; td < 2; ++td)
          accO[tn][td] = MFMA16(eC[tn][kf], bb[td], accO[tn][td]);
    }
  }
  // epilogue: direct fp32 out (init with V0 term, or read-add in later pass)
  float* Op = out + ((size_t)b << 20);
  const __bf16* V0 = Vb + ((size_t)b << 20);
  const bool init = (nc >= mtLo);
#pragma unroll
  for (int tn = 0; tn < 2; ++tn)
#pragma unroll
    for (int td = 0; td < 2; ++td) {
      int col = dh * 128 + w * 32 + td * 16 + ln;
      float c0 = init ? (float)V0[col] * (1.0f / 4096.0f) : 0.f;
#pragma unroll
      for (int r = 0; r < 4; ++r) {
        int row = n0 + tn * 16 + quad * 4 + r;
        float* pp = &Op[(size_t)row * DIM + col];
        float v = accO[tn][td][r] + c0;
        if (!init) v += *pp;
        *pp = v;
      }
    }
}

// ---------------------------------------------------------------- launch
extern "C" void kernel_launch(void* const* d_in, const int* in_sizes, int n_in,
                              void* d_out, int out_size, void* d_ws, size_t ws_size,
                              hipStream_t stream) {
  const float* x = (const float*)d_in[0];
  const float* Wq = (const float*)d_in[1];
  const float* Wk = (const float*)d_in[2];
  const float* Wv = (const float*)d_in[3];
  float* out = (float*)d_out;
  char* ws = (char*)d_ws;
  __bf16* Qb = (__bf16*)(ws);                             // 8 MB
  __bf16* Kb = (__bf16*)(ws + (8u << 20));                // 8 MB
  __bf16* Vb = (__bf16*)(ws + (16u << 20));               // 8 MB
  __bf16* VpT = (__bf16*)(ws + (24u << 20));              // 8 MB (blocked+swizzled)
  float* colsum = (float*)(ws + (32u << 20));             // 64 KB
  __bf16* Wb = (__bf16*)(ws + (32u << 20) + (1u << 16));  // 384 KB
  const size_t base2 = (32u << 20) + (1u << 16) + (384u << 10);
  __bf16* E = (__bf16*)(ws + base2);
  // pass schedule by ws capacity (constant per session -> capture-safe)
  const size_t fullE = (size_t)4 * 2080 * 4096 * sizeof(__bf16);  // 68.2 MB
  int nPass, lo[3], hi[3];
  if (ws_size >= base2 + fullE) {
    nPass = 1; lo[0] = 0; hi[0] = 64;
  } else {  // 3 near-equal-tile passes
    nPass = 3;
    lo[0] = 0;  hi[0] = 37;
    lo[1] = 37; hi[1] = 53;
    lo[2] = 53; hi[2] = 64;
  }

  k_prep<<<dim3(768), dim3(256), 0, stream>>>(Wq, Wk, Wv, Wb, colsum);
  k_qkv<<<dim3(256), dim3(256), 0, stream>>>(x, Wb, Qb, Kb, Vb);
  for (int p = 0; p < nPass; ++p) {
    const int nmt = hi[p] - lo[p];
    const int triLo = tri(lo[p]);
    const int ntiles = tri(hi[p]) - triLo;
    k_scores<<<dim3(16 * nmt), dim3(256), 0, stream>>>(Qb, Kb, E, colsum,
                                                       lo[p], triLo, ntiles);
    k_vpt<<<dim3(nmt, 4, 4), dim3(256), 0, stream>>>(Vb, colsum, VpT, lo[p]);
    k_pv<<<dim3(16 * hi[p]), dim3(256), 0, stream>>>(E, VpT, Vb, out,
                                                     lo[p], hi[p], triLo, ntiles);
  }
}